// Round 4
// baseline (642.713 us; speedup 1.0000x reference)
//
#include <hip/hip_runtime.h>
#include <hip/hip_bf16.h>

#define T_TOK 4096
#define HID   1024
#define INTER 2048
#define NE    8
#define NE1   9      // 8 routed + 1 shared expert
#define BK    64     // K-tile (bf16 elems); XOR-swizzled chunks, global_load_lds staged
#define MAXT  104    // max 128-row m-tiles: <=72 routed + 32 shared

typedef __attribute__((ext_vector_type(8))) short short8;
typedef __attribute__((ext_vector_type(8))) unsigned short ushort8v;
typedef __attribute__((ext_vector_type(4))) float f32x4;

__device__ __forceinline__ unsigned short f2bf(float f) {
    __hip_bfloat16 h = __float2bfloat16(f);
    return __builtin_bit_cast(unsigned short, h);
}
__device__ __forceinline__ float bf2f(unsigned short u) {
    unsigned int v = ((unsigned int)u) << 16;
    return __builtin_bit_cast(float, v);
}
__device__ __forceinline__ float sigm(float x) { return 1.0f / (1.0f + __expf(-x)); }

// async global->LDS, 16B per lane. LDS dest = wave-uniform base + lane*16.
__device__ __forceinline__ void async_ld16(const void* g, void* l) {
    __builtin_amdgcn_global_load_lds(
        (const __attribute__((address_space(1))) unsigned int*)g,
        (__attribute__((address_space(3))) unsigned int*)l, 16, 0, 0);
}

// ---------- merged fp32 -> bf16 casts for the 3 shared-expert weights ----------
__global__ __launch_bounds__(256) void
prep_cast(const float* __restrict__ s0, const float* __restrict__ s1, const float* __restrict__ s2,
          unsigned short* __restrict__ d0, unsigned short* __restrict__ d1, unsigned short* __restrict__ d2) {
    int seg = blockIdx.y;
    const float* s = (seg == 0) ? s0 : (seg == 1) ? s1 : s2;
    unsigned short* d = (seg == 0) ? d0 : (seg == 1) ? d1 : d2;
    int i = blockIdx.x * 256 + threadIdx.x;     // 2048*1024/4 float4 per seg
    float4 v = ((const float4*)s)[i];
    ushort4 o;
    o.x = f2bf(v.x); o.y = f2bf(v.y); o.z = f2bf(v.z); o.w = f2bf(v.w);
    ((ushort4*)d)[i] = o;
}

// ---------- fp32 [K][N] -> bf16 [N][K] transpose+cast, 128k x 64n tiles ----------
__global__ __launch_bounds__(256) void
transpose_cast(const float* __restrict__ W, unsigned short* __restrict__ Wt,
               int K, int N, size_t in_stride_e, size_t out_stride_e) {
    __shared__ float tile[128][65];
    const float* Wb = W + (size_t)blockIdx.z * in_stride_e;
    unsigned short* Wo = Wt + (size_t)blockIdx.z * out_stride_e;
    int n0 = blockIdx.x * 64, k0 = blockIdx.y * 128;
    int tid = threadIdx.x;
    int r = tid >> 4, c = tid & 15;
#pragma unroll
    for (int i = 0; i < 8; i++) {              // read: 128 k-rows x 64 n (256B segs)
        int k = i * 16 + r;
        float4 v = *(const float4*)(Wb + (size_t)(k0 + k) * N + n0 + c * 4);
        tile[k][c * 4 + 0] = v.x; tile[k][c * 4 + 1] = v.y;
        tile[k][c * 4 + 2] = v.z; tile[k][c * 4 + 3] = v.w;
    }
    __syncthreads();
#pragma unroll
    for (int i = 0; i < 4; i++) {              // write: 64 n-rows x 128 k (256B segs)
        int n = i * 16 + r;
        ushort8v o;
#pragma unroll
        for (int j = 0; j < 8; j++) o[j] = f2bf(tile[c * 8 + j][n]);
        *(ushort8v*)(Wo + (size_t)(n0 + n) * K + k0 + c * 8) = o;
    }
}

// ---------------- router: logits + top2 + scatter + inverse map ----------------
__global__ void router_kernel(const float* __restrict__ x, const float* __restrict__ rw,
                              float* __restrict__ logits_out,
                              int* __restrict__ cnt, int* __restrict__ tok_list,
                              float* __restrict__ score_list, int2* __restrict__ inv) {
    int wave = threadIdx.x >> 6;
    int lane = threadIdx.x & 63;
    int t = blockIdx.x * 4 + wave;

    float dot[NE];
#pragma unroll
    for (int e = 0; e < NE; e++) dot[e] = 0.0f;
    const float4* xv = (const float4*)(x + (size_t)t * HID);
    const float4* wv = (const float4*)rw;
#pragma unroll
    for (int j = 0; j < 4; j++) {
        float4 xc = xv[j * 64 + lane];
#pragma unroll
        for (int e = 0; e < NE; e++) {
            float4 wc = wv[e * 256 + j * 64 + lane];
            dot[e] += xc.x * wc.x + xc.y * wc.y + xc.z * wc.z + xc.w * wc.w;
        }
    }
#pragma unroll
    for (int e = 0; e < NE; e++) {
        float v = dot[e];
        for (int m = 1; m < 64; m <<= 1) v += __shfl_xor(v, m, 64);
        dot[e] = v;
    }
    if (lane == 0) {
        float v1 = -1e30f, v2 = -1e30f; int i1 = 0, i2 = 0;
#pragma unroll
        for (int e = 0; e < NE; e++) {
            float v = dot[e];
            logits_out[(size_t)t * NE + e] = v;
            if (v > v1) { v2 = v1; i2 = i1; v1 = v; i1 = e; }
            else if (v > v2) { v2 = v; i2 = e; }
        }
        float s1 = 1.0f / (1.0f + expf(-v1));
        float s2 = 1.0f / (1.0f + expf(-v2));
        int p1 = atomicAdd(&cnt[i1], 1);
        tok_list[i1 * T_TOK + p1] = t; score_list[i1 * T_TOK + p1] = s1;
        int p2 = atomicAdd(&cnt[i2], 1);
        tok_list[i2 * T_TOK + p2] = t; score_list[i2 * T_TOK + p2] = s2;
        inv[t] = make_int2((i1 << 16) | p1, (i2 << 16) | p2);
    }
}

// -------- finalize: pad lists, shared-expert fill, prefix offsets, tile table --------
__global__ void finalize_kernel(const int* __restrict__ cnt, int* __restrict__ offs,
                                int* __restrict__ tiletab,
                                int* __restrict__ tok_list, float* __restrict__ score_list) {
    __shared__ int s_cnt[NE], s_pad[NE];
    int tid = threadIdx.x;
    if (tid == 0) {
        int o = 0, nt = 0;
        for (int e = 0; e < NE1; e++) {
            int c = (e == NE) ? T_TOK : cnt[e];
            int p = (c + 127) & ~127;
            offs[e] = o;
            for (int m = 0; m < (p >> 7); m++) tiletab[nt++] = (e << 8) | m;
            if (e < NE) { s_cnt[e] = c; s_pad[e] = p; }
            o += p;
        }
        for (; nt < MAXT; nt++) tiletab[nt] = -1;
    }
    for (int i = tid; i < T_TOK; i += blockDim.x) {   // shared expert: identity list
        tok_list[NE * T_TOK + i] = i;
        score_list[NE * T_TOK + i] = 1.0f;
    }
    __syncthreads();
    for (int e = 0; e < NE; e++) {
        for (int i = s_cnt[e] + tid; i < s_pad[e]; i += blockDim.x) {
            tok_list[e * T_TOK + i] = 0;
            score_list[e * T_TOK + i] = 0.0f;
        }
    }
}

// -------- gather: xg[slot][k] = bf16(x[tok[slot]][k]) — contiguous A for g1 --------
__global__ __launch_bounds__(256) void
gather_kernel(const float* __restrict__ x, const int* __restrict__ tiletab,
              const int* __restrict__ offs, const int* __restrict__ tok_list,
              unsigned short* __restrict__ xg) {
    int tt = tiletab[blockIdx.x];
    if (tt < 0) return;
    int e = tt >> 8, mt = tt & 255;
    size_t rowbase = (size_t)offs[e] + (size_t)mt * 128;
    int tid = threadIdx.x;
    int c = tid & 7, rl = tid >> 3;   // 8 threads per row, 32 rows per pass
#pragma unroll
    for (int pass = 0; pass < 4; pass++) {
        int r = pass * 32 + rl;
        int tok = tok_list[e * T_TOK + mt * 128 + r];
        const float4* src = (const float4*)(x + (size_t)tok * HID);
        ushort4* dst = (ushort4*)(xg + (rowbase + r) * HID);
#pragma unroll
        for (int p = 0; p < 32; p++) {
            float4 v = src[p * 8 + c];
            ushort4 o;
            o.x = f2bf(v.x); o.y = f2bf(v.y); o.z = f2bf(v.z); o.w = f2bf(v.w);
            dst[p * 8 + c] = o;
        }
    }
}

// ---------------- unified GEMM1: xg @ {gate,up}^T, fused score+SwiGLU ----------------
__global__ __launch_bounds__(256) void
moe_g1(const unsigned short* __restrict__ xg, const unsigned short* __restrict__ wg_t,
       const int* __restrict__ tiletab, const int* __restrict__ offs,
       const float* __restrict__ score_list, unsigned short* __restrict__ h) {
    int tt = tiletab[blockIdx.y];
    if (tt < 0) return;
    int e = tt >> 8, mt = tt & 255;
    int nt = blockIdx.x;  // 0..31, 64 intermediate cols

    __shared__ unsigned short As[128 * BK];   // 16 KB
    __shared__ unsigned short Bg[64 * BK];    // 8 KB
    __shared__ unsigned short Bu[64 * BK];    // 8 KB
    __shared__ float s_sc[128];

    int tid = threadIdx.x, lane = tid & 63;
    int wid = tid >> 6, wm = wid >> 1, wn = wid & 1;
    size_t rowbase = (size_t)offs[e] + (size_t)mt * 128;

    if (tid < 128) s_sc[tid] = score_list[e * T_TOK + mt * 128 + tid];

    const unsigned short* wg = wg_t + (size_t)e * (4096u * 1024u);
    int rsub = tid >> 3;                       // 0..31 staging row within issue
    int csw = (tid & 7) ^ (rsub & 7);          // XOR-swizzled source chunk
    const unsigned short* pA[4];
#pragma unroll
    for (int i = 0; i < 4; i++)
        pA[i] = xg + (rowbase + i * 32 + rsub) * HID + csw * 8;
    const unsigned short* pBg[2];
    const unsigned short* pBu[2];
#pragma unroll
    for (int i = 0; i < 2; i++) {
        pBg[i] = wg + (size_t)(nt * 64 + i * 32 + rsub) * HID + csw * 8;
        pBu[i] = wg + (size_t)(INTER + nt * 64 + i * 32 + rsub) * HID + csw * 8;
    }
    unsigned short* lA = As + tid * 8;         // + i*2048 per issue
    unsigned short* lBg = Bg + tid * 8;
    unsigned short* lBu = Bu + tid * 8;

    f32x4 accg[4][2], accu[4][2];
#pragma unroll
    for (int i = 0; i < 4; i++)
#pragma unroll
        for (int j = 0; j < 2; j++) { accg[i][j] = (f32x4)(0.0f); accu[i][j] = (f32x4)(0.0f); }

    int mrow = lane & 15, q = lane >> 4, x7 = lane & 7;
    for (int k0 = 0; k0 < HID; k0 += BK) {
#pragma unroll
        for (int i = 0; i < 4; i++) async_ld16(pA[i] + k0, lA + i * 2048);
#pragma unroll
        for (int i = 0; i < 2; i++) {
            async_ld16(pBg[i] + k0, lBg + i * 2048);
            async_ld16(pBu[i] + k0, lBu + i * 2048);
        }
        __syncthreads();
#pragma unroll
        for (int ksub = 0; ksub < 2; ksub++) {
            int ch = ((ksub * 4 + q) ^ x7) * 8;
            short8 af[4], bg[2], bu[2];
#pragma unroll
            for (int mi = 0; mi < 4; mi++)
                af[mi] = *(const short8*)(As + (wm * 64 + mi * 16 + mrow) * BK + ch);
#pragma unroll
            for (int ni = 0; ni < 2; ni++) {
                bg[ni] = *(const short8*)(Bg + (wn * 32 + ni * 16 + mrow) * BK + ch);
                bu[ni] = *(const short8*)(Bu + (wn * 32 + ni * 16 + mrow) * BK + ch);
            }
#pragma unroll
            for (int mi = 0; mi < 4; mi++)
#pragma unroll
                for (int ni = 0; ni < 2; ni++) {
                    accg[mi][ni] = __builtin_amdgcn_mfma_f32_16x16x32_bf16(af[mi], bg[ni], accg[mi][ni], 0, 0, 0);
                    accu[mi][ni] = __builtin_amdgcn_mfma_f32_16x16x32_bf16(af[mi], bu[ni], accu[mi][ni], 0, 0, 0);
                }
        }
        __syncthreads();
    }
    int ibase = nt * 64 + wn * 32;
#pragma unroll
    for (int mi = 0; mi < 4; mi++)
#pragma unroll
        for (int ni = 0; ni < 2; ni++)
#pragma unroll
            for (int r = 0; r < 4; r++) {
                int m = wm * 64 + mi * 16 + (lane >> 4) * 4 + r;
                int i = ibase + ni * 16 + (lane & 15);
                float s = s_sc[m];
                float g = accg[mi][ni][r] * s;
                float u = accu[mi][ni][r] * s;
                h[(rowbase + m) * INTER + i] = f2bf(u * g * sigm(g));
            }
}

// ---------------- unified GEMM2: h @ down^T -> dense r_out (no atomics) ----------------
__global__ __launch_bounds__(256) void
moe_g2(const unsigned short* __restrict__ h, const unsigned short* __restrict__ wd_t,
       const int* __restrict__ tiletab, const int* __restrict__ offs,
       unsigned short* __restrict__ r_out) {
    int tt = tiletab[blockIdx.y];
    if (tt < 0) return;
    int e = tt >> 8, mt = tt & 255;
    int nt = blockIdx.x;  // 0..7, 128 H-cols

    __shared__ unsigned short As[128 * BK];   // 16 KB
    __shared__ unsigned short Bs[128 * BK];   // 16 KB

    int tid = threadIdx.x, lane = tid & 63;
    int wid = tid >> 6, wm = wid >> 1, wn = wid & 1;
    size_t rowbase = (size_t)offs[e] + (size_t)mt * 128;

    const unsigned short* wd = wd_t + (size_t)e * (1024u * 2048u);
    int rsub = tid >> 3;
    int csw = (tid & 7) ^ (rsub & 7);
    const unsigned short* pA[4];
    const unsigned short* pB[4];
#pragma unroll
    for (int i = 0; i < 4; i++) {
        pA[i] = h + (rowbase + i * 32 + rsub) * INTER + csw * 8;
        pB[i] = wd + (size_t)(nt * 128 + i * 32 + rsub) * INTER + csw * 8;
    }
    unsigned short* lA = As + tid * 8;
    unsigned short* lB = Bs + tid * 8;

    f32x4 acc[4][4];
#pragma unroll
    for (int i = 0; i < 4; i++)
#pragma unroll
        for (int j = 0; j < 4; j++) acc[i][j] = (f32x4)(0.0f);

    int mrow = lane & 15, q = lane >> 4, x7 = lane & 7;
    for (int k0 = 0; k0 < INTER; k0 += BK) {
#pragma unroll
        for (int i = 0; i < 4; i++) {
            async_ld16(pA[i] + k0, lA + i * 2048);
            async_ld16(pB[i] + k0, lB + i * 2048);
        }
        __syncthreads();
#pragma unroll
        for (int ksub = 0; ksub < 2; ksub++) {
            int ch = ((ksub * 4 + q) ^ x7) * 8;
            short8 af[4], bf_[4];
#pragma unroll
            for (int mi = 0; mi < 4; mi++)
                af[mi] = *(const short8*)(As + (wm * 64 + mi * 16 + mrow) * BK + ch);
#pragma unroll
            for (int ni = 0; ni < 4; ni++)
                bf_[ni] = *(const short8*)(Bs + (wn * 64 + ni * 16 + mrow) * BK + ch);
#pragma unroll
            for (int mi = 0; mi < 4; mi++)
#pragma unroll
                for (int ni = 0; ni < 4; ni++)
                    acc[mi][ni] = __builtin_amdgcn_mfma_f32_16x16x32_bf16(af[mi], bf_[ni], acc[mi][ni], 0, 0, 0);
        }
        __syncthreads();
    }
#pragma unroll
    for (int mi = 0; mi < 4; mi++)
#pragma unroll
        for (int ni = 0; ni < 4; ni++)
#pragma unroll
            for (int r = 0; r < 4; r++) {
                int m = wm * 64 + mi * 16 + (lane >> 4) * 4 + r;
                int n = nt * 128 + wn * 64 + ni * 16 + (lane & 15);
                r_out[(rowbase + m) * HID + n] = f2bf(acc[mi][ni][r]);
            }
}

// ---------------- combine: out[t] = shared + two routed contributions ----------------
__global__ void combine_kernel(const unsigned short* __restrict__ r_out,
                               const int2* __restrict__ inv, const int* __restrict__ offs,
                               float* __restrict__ out) {
    int t = blockIdx.x, tid = threadIdx.x;
    int2 iv = inv[t];
    size_t r1 = (size_t)(offs[iv.x >> 16] + (iv.x & 0xffff)) * HID;
    size_t r2 = (size_t)(offs[iv.y >> 16] + (iv.y & 0xffff)) * HID;
    size_t rs = (size_t)(offs[NE] + t) * HID;
    int i = tid * 4;
    ushort4 a = *(const ushort4*)(r_out + r1 + i);
    ushort4 b = *(const ushort4*)(r_out + r2 + i);
    ushort4 c = *(const ushort4*)(r_out + rs + i);
    float4 o;
    o.x = bf2f(a.x) + bf2f(b.x) + bf2f(c.x);
    o.y = bf2f(a.y) + bf2f(b.y) + bf2f(c.y);
    o.z = bf2f(a.z) + bf2f(b.z) + bf2f(c.z);
    o.w = bf2f(a.w) + bf2f(b.w) + bf2f(c.w);
    *(float4*)(out + (size_t)t * HID + i) = o;
}

extern "C" void kernel_launch(void* const* d_in, const int* in_sizes, int n_in,
                              void* d_out, int out_size, void* d_ws, size_t ws_size,
                              hipStream_t stream) {
    const float* x   = (const float*)d_in[0];
    const float* rw  = (const float*)d_in[1];
    const float* gup = (const float*)d_in[2];
    const float* dwn = (const float*)d_in[3];
    const float* sgw = (const float*)d_in[4];
    const float* suw = (const float*)d_in[5];
    const float* sdw = (const float*)d_in[6];
    float* out = (float*)d_out;
    float* logits = out + (size_t)T_TOK * HID;

    char* ws = (char*)d_ws;
    int*   cnt        = (int*)(ws + 0);
    int*   offs       = (int*)(ws + 64);
    int*   tiletab    = (int*)(ws + 128);
    int2*  inv        = (int2*)(ws + 4096);
    int*   tok_list   = (int*)(ws + 65536);                       // 9*4096*4
    float* score_list = (float*)(ws + 212992);                    // 9*4096*4
    unsigned short* w_gup_t = (unsigned short*)(ws + 524288);     // 9*4096*1024*2 = 75497472
    unsigned short* w_dwn_t = (unsigned short*)(ws + 76021760);   // 9*1024*2048*2 = 37748736
    unsigned short* xg      = (unsigned short*)(ws + 113770496);  // 13312*1024*2  = 27262976
    unsigned short* h       = (unsigned short*)(ws + 141033472);  // 13312*2048*2  = 54525952
    unsigned short* r_out   = (unsigned short*)(ws + 195559424);  // 13312*1024*2  = 27262976

    hipMemsetAsync(cnt, 0, NE * sizeof(int), stream);

    // weight prep: transpose routed weights to bf16 [N][K]; shared already [N][K]
    {
        dim3 g(4096 / 64, 1024 / 128, NE);
        transpose_cast<<<g, 256, 0, stream>>>(gup, w_gup_t, 1024, 4096,
                                              (size_t)1024 * 4096, (size_t)4096 * 1024);
    }
    {
        dim3 g(1024 / 64, 2048 / 128, NE);
        transpose_cast<<<g, 256, 0, stream>>>(dwn, w_dwn_t, 2048, 1024,
                                              (size_t)2048 * 1024, (size_t)1024 * 2048);
    }
    unsigned short* wg8 = w_gup_t + (size_t)NE * 4096 * 1024;
    unsigned short* wd8 = w_dwn_t + (size_t)NE * 1024 * 2048;
    {
        dim3 g(2048, 3);
        prep_cast<<<g, 256, 0, stream>>>(sgw, suw, sdw, wg8, wg8 + 2048 * 1024, wd8);
    }

    router_kernel<<<T_TOK / 4, 256, 0, stream>>>(x, rw, logits, cnt, tok_list, score_list, inv);
    finalize_kernel<<<1, 256, 0, stream>>>(cnt, offs, tiletab, tok_list, score_list);
    gather_kernel<<<MAXT, 256, 0, stream>>>(x, tiletab, offs, tok_list, xg);

    dim3 g1(INTER / 64, MAXT);
    moe_g1<<<g1, 256, 0, stream>>>(xg, w_gup_t, tiletab, offs, score_list, h);
    dim3 g2(HID / 128, MAXT);
    moe_g2<<<g2, 256, 0, stream>>>(h, w_dwn_t, tiletab, offs, r_out);
    combine_kernel<<<T_TOK, 256, 0, stream>>>(r_out, inv, offs, out);
}

// Round 5
// 641.638 us; speedup vs baseline: 1.0017x; 1.0017x over previous
//
#include <hip/hip_runtime.h>
#include <hip/hip_bf16.h>

#define T_TOK 4096
#define HID   1024
#define INTER 2048
#define NE    8
#define NE1   9      // 8 routed + 1 shared expert
#define BK    64     // K-tile (bf16 elems); XOR-swizzled chunks, global_load_lds staged
#define MAXT  104    // max 128-row m-tiles: <=72 routed + 32 shared (8*13 exactly)

typedef __attribute__((ext_vector_type(8))) short short8;
typedef __attribute__((ext_vector_type(8))) unsigned short ushort8v;
typedef __attribute__((ext_vector_type(4))) float f32x4;

__device__ __forceinline__ unsigned short f2bf(float f) {
    __hip_bfloat16 h = __float2bfloat16(f);
    return __builtin_bit_cast(unsigned short, h);
}
__device__ __forceinline__ float bf2f(unsigned short u) {
    unsigned int v = ((unsigned int)u) << 16;
    return __builtin_bit_cast(float, v);
}
__device__ __forceinline__ float sigm(float x) { return 1.0f / (1.0f + __expf(-x)); }

// async global->LDS, 16B per lane. LDS dest = wave-uniform base + lane*16.
__device__ __forceinline__ void async_ld16(const void* g, void* l) {
    __builtin_amdgcn_global_load_lds(
        (const __attribute__((address_space(1))) unsigned int*)g,
        (__attribute__((address_space(3))) unsigned int*)l, 16, 0, 0);
}

// ---------- merged fp32 -> bf16 casts for the 3 shared-expert weights ----------
__global__ __launch_bounds__(256) void
prep_cast(const float* __restrict__ s0, const float* __restrict__ s1, const float* __restrict__ s2,
          unsigned short* __restrict__ d0, unsigned short* __restrict__ d1, unsigned short* __restrict__ d2) {
    int seg = blockIdx.y;
    const float* s = (seg == 0) ? s0 : (seg == 1) ? s1 : s2;
    unsigned short* d = (seg == 0) ? d0 : (seg == 1) ? d1 : d2;
    int i = blockIdx.x * 256 + threadIdx.x;     // 2048*1024/4 float4 per seg
    float4 v = ((const float4*)s)[i];
    ushort4 o;
    o.x = f2bf(v.x); o.y = f2bf(v.y); o.z = f2bf(v.z); o.w = f2bf(v.w);
    ((ushort4*)d)[i] = o;
}

// ---------- fp32 [K][N] -> bf16 [N][K] transpose+cast, 128k x 64n tiles ----------
__global__ __launch_bounds__(256) void
transpose_cast(const float* __restrict__ W, unsigned short* __restrict__ Wt,
               int K, int N, size_t in_stride_e, size_t out_stride_e) {
    __shared__ float tile[128][65];
    const float* Wb = W + (size_t)blockIdx.z * in_stride_e;
    unsigned short* Wo = Wt + (size_t)blockIdx.z * out_stride_e;
    int n0 = blockIdx.x * 64, k0 = blockIdx.y * 128;
    int tid = threadIdx.x;
    int r = tid >> 4, c = tid & 15;
#pragma unroll
    for (int i = 0; i < 8; i++) {              // read: 128 k-rows x 64 n (256B segs)
        int k = i * 16 + r;
        float4 v = *(const float4*)(Wb + (size_t)(k0 + k) * N + n0 + c * 4);
        tile[k][c * 4 + 0] = v.x; tile[k][c * 4 + 1] = v.y;
        tile[k][c * 4 + 2] = v.z; tile[k][c * 4 + 3] = v.w;
    }
    __syncthreads();
#pragma unroll
    for (int i = 0; i < 4; i++) {              // write: 64 n-rows x 128 k (256B segs)
        int n = i * 16 + r;
        ushort8v o;
#pragma unroll
        for (int j = 0; j < 8; j++) o[j] = f2bf(tile[c * 8 + j][n]);
        *(ushort8v*)(Wo + (size_t)(n0 + n) * K + k0 + c * 8) = o;
    }
}

// ---------------- router: logits + top2 + scatter + inverse map ----------------
__global__ void router_kernel(const float* __restrict__ x, const float* __restrict__ rw,
                              float* __restrict__ logits_out,
                              int* __restrict__ cnt, int* __restrict__ tok_list,
                              float* __restrict__ score_list, int2* __restrict__ inv) {
    int wave = threadIdx.x >> 6;
    int lane = threadIdx.x & 63;
    int t = blockIdx.x * 4 + wave;

    float dot[NE];
#pragma unroll
    for (int e = 0; e < NE; e++) dot[e] = 0.0f;
    const float4* xv = (const float4*)(x + (size_t)t * HID);
    const float4* wv = (const float4*)rw;
#pragma unroll
    for (int j = 0; j < 4; j++) {
        float4 xc = xv[j * 64 + lane];
#pragma unroll
        for (int e = 0; e < NE; e++) {
            float4 wc = wv[e * 256 + j * 64 + lane];
            dot[e] += xc.x * wc.x + xc.y * wc.y + xc.z * wc.z + xc.w * wc.w;
        }
    }
#pragma unroll
    for (int e = 0; e < NE; e++) {
        float v = dot[e];
        for (int m = 1; m < 64; m <<= 1) v += __shfl_xor(v, m, 64);
        dot[e] = v;
    }
    if (lane == 0) {
        float v1 = -1e30f, v2 = -1e30f; int i1 = 0, i2 = 0;
#pragma unroll
        for (int e = 0; e < NE; e++) {
            float v = dot[e];
            logits_out[(size_t)t * NE + e] = v;
            if (v > v1) { v2 = v1; i2 = i1; v1 = v; i1 = e; }
            else if (v > v2) { v2 = v; i2 = e; }
        }
        float s1 = 1.0f / (1.0f + expf(-v1));
        float s2 = 1.0f / (1.0f + expf(-v2));
        int p1 = atomicAdd(&cnt[i1], 1);
        tok_list[i1 * T_TOK + p1] = t; score_list[i1 * T_TOK + p1] = s1;
        int p2 = atomicAdd(&cnt[i2], 1);
        tok_list[i2 * T_TOK + p2] = t; score_list[i2 * T_TOK + p2] = s2;
        inv[t] = make_int2((i1 << 16) | p1, (i2 << 16) | p2);
    }
}

// -------- finalize: pad lists, shared-expert fill, prefix offsets, tile table --------
__global__ void finalize_kernel(const int* __restrict__ cnt, int* __restrict__ offs,
                                int* __restrict__ tiletab,
                                int* __restrict__ tok_list, float* __restrict__ score_list) {
    __shared__ int s_cnt[NE], s_pad[NE];
    int tid = threadIdx.x;
    if (tid == 0) {
        int o = 0, nt = 0;
        for (int e = 0; e < NE1; e++) {
            int c = (e == NE) ? T_TOK : cnt[e];
            int p = (c + 127) & ~127;
            offs[e] = o;
            for (int m = 0; m < (p >> 7); m++) tiletab[nt++] = (e << 8) | m;
            if (e < NE) { s_cnt[e] = c; s_pad[e] = p; }
            o += p;
        }
        for (; nt < MAXT; nt++) tiletab[nt] = -1;
    }
    for (int i = tid; i < T_TOK; i += blockDim.x) {   // shared expert: identity list
        tok_list[NE * T_TOK + i] = i;
        score_list[NE * T_TOK + i] = 1.0f;
    }
    __syncthreads();
    for (int e = 0; e < NE; e++) {
        for (int i = s_cnt[e] + tid; i < s_pad[e]; i += blockDim.x) {
            tok_list[e * T_TOK + i] = 0;
            score_list[e * T_TOK + i] = 0.0f;
        }
    }
}

// -------- gather: xg[slot][k] = bf16(x[tok[slot]][k]) — contiguous A for g1 --------
__global__ __launch_bounds__(256) void
gather_kernel(const float* __restrict__ x, const int* __restrict__ tiletab,
              const int* __restrict__ offs, const int* __restrict__ tok_list,
              unsigned short* __restrict__ xg) {
    int tt = tiletab[blockIdx.x];
    if (tt < 0) return;
    int e = tt >> 8, mt = tt & 255;
    size_t rowbase = (size_t)offs[e] + (size_t)mt * 128;
    int tid = threadIdx.x;
    int c = tid & 7, rl = tid >> 3;   // 8 threads per row, 32 rows per pass
#pragma unroll
    for (int pass = 0; pass < 4; pass++) {
        int r = pass * 32 + rl;
        int tok = tok_list[e * T_TOK + mt * 128 + r];
        const float4* src = (const float4*)(x + (size_t)tok * HID);
        ushort4* dst = (ushort4*)(xg + (rowbase + r) * HID);
#pragma unroll
        for (int p = 0; p < 32; p++) {
            float4 v = src[p * 8 + c];
            ushort4 o;
            o.x = f2bf(v.x); o.y = f2bf(v.y); o.z = f2bf(v.z); o.w = f2bf(v.w);
            dst[p * 8 + c] = o;
        }
    }
}

// ---------------- unified GEMM1: xg @ {gate,up}^T, fused score+SwiGLU ----------------
// Grid: 3328 linear blocks, XCD-swizzled: same m-tile -> same (id%8) -> same XCD,
// so the A-tile is served from XCD-local L2 instead of Infinity Cache.
__global__ __launch_bounds__(256) void
moe_g1(const unsigned short* __restrict__ xg, const unsigned short* __restrict__ wg_t,
       const int* __restrict__ tiletab, const int* __restrict__ offs,
       const float* __restrict__ score_list, unsigned short* __restrict__ h) {
    int id = blockIdx.x;
    int xcd = id & 7, q = id >> 3;
    int nt = q & 31;                       // 0..31, 64 intermediate cols
    int mslot = (q >> 5) * 8 + xcd;        // 0..103
    int tt = tiletab[mslot];
    if (tt < 0) return;
    int e = tt >> 8, mt = tt & 255;

    __shared__ unsigned short As[128 * BK];   // 16 KB
    __shared__ unsigned short Bg[64 * BK];    // 8 KB
    __shared__ unsigned short Bu[64 * BK];    // 8 KB
    __shared__ float s_sc[128];

    int tid = threadIdx.x, lane = tid & 63;
    int wid = tid >> 6, wm = wid >> 1, wn = wid & 1;
    size_t rowbase = (size_t)offs[e] + (size_t)mt * 128;

    if (tid < 128) s_sc[tid] = score_list[e * T_TOK + mt * 128 + tid];

    const unsigned short* wg = wg_t + (size_t)e * (4096u * 1024u);
    int rsub = tid >> 3;                       // 0..31 staging row within issue
    int csw = (tid & 7) ^ (rsub & 7);          // XOR-swizzled source chunk
    const unsigned short* pA[4];
#pragma unroll
    for (int i = 0; i < 4; i++)
        pA[i] = xg + (rowbase + i * 32 + rsub) * HID + csw * 8;
    const unsigned short* pBg[2];
    const unsigned short* pBu[2];
#pragma unroll
    for (int i = 0; i < 2; i++) {
        pBg[i] = wg + (size_t)(nt * 64 + i * 32 + rsub) * HID + csw * 8;
        pBu[i] = wg + (size_t)(INTER + nt * 64 + i * 32 + rsub) * HID + csw * 8;
    }
    unsigned short* lA = As + tid * 8;         // + i*2048 per issue
    unsigned short* lBg = Bg + tid * 8;
    unsigned short* lBu = Bu + tid * 8;

    f32x4 accg[4][2], accu[4][2];
#pragma unroll
    for (int i = 0; i < 4; i++)
#pragma unroll
        for (int j = 0; j < 2; j++) { accg[i][j] = (f32x4)(0.0f); accu[i][j] = (f32x4)(0.0f); }

    int mrow = lane & 15, qq = lane >> 4, x7 = lane & 7;
    for (int k0 = 0; k0 < HID; k0 += BK) {
#pragma unroll
        for (int i = 0; i < 4; i++) async_ld16(pA[i] + k0, lA + i * 2048);
#pragma unroll
        for (int i = 0; i < 2; i++) {
            async_ld16(pBg[i] + k0, lBg + i * 2048);
            async_ld16(pBu[i] + k0, lBu + i * 2048);
        }
        __syncthreads();
#pragma unroll
        for (int ksub = 0; ksub < 2; ksub++) {
            int ch = ((ksub * 4 + qq) ^ x7) * 8;
            short8 af[4], bg[2], bu[2];
#pragma unroll
            for (int mi = 0; mi < 4; mi++)
                af[mi] = *(const short8*)(As + (wm * 64 + mi * 16 + mrow) * BK + ch);
#pragma unroll
            for (int ni = 0; ni < 2; ni++) {
                bg[ni] = *(const short8*)(Bg + (wn * 32 + ni * 16 + mrow) * BK + ch);
                bu[ni] = *(const short8*)(Bu + (wn * 32 + ni * 16 + mrow) * BK + ch);
            }
#pragma unroll
            for (int mi = 0; mi < 4; mi++)
#pragma unroll
                for (int ni = 0; ni < 2; ni++) {
                    accg[mi][ni] = __builtin_amdgcn_mfma_f32_16x16x32_bf16(af[mi], bg[ni], accg[mi][ni], 0, 0, 0);
                    accu[mi][ni] = __builtin_amdgcn_mfma_f32_16x16x32_bf16(af[mi], bu[ni], accu[mi][ni], 0, 0, 0);
                }
        }
        __syncthreads();
    }
    int ibase = nt * 64 + wn * 32;
#pragma unroll
    for (int mi = 0; mi < 4; mi++)
#pragma unroll
        for (int ni = 0; ni < 2; ni++)
#pragma unroll
            for (int r = 0; r < 4; r++) {
                int m = wm * 64 + mi * 16 + (lane >> 4) * 4 + r;
                int i = ibase + ni * 16 + (lane & 15);
                float s = s_sc[m];
                float g = accg[mi][ni][r] * s;
                float u = accu[mi][ni][r] * s;
                h[(rowbase + m) * INTER + i] = f2bf(u * g * sigm(g));
            }
}

// ---------------- unified GEMM2: h @ down^T -> dense r_out (no atomics) ----------------
// Grid: 832 linear blocks, XCD-swizzled like g1.
__global__ __launch_bounds__(256) void
moe_g2(const unsigned short* __restrict__ h, const unsigned short* __restrict__ wd_t,
       const int* __restrict__ tiletab, const int* __restrict__ offs,
       unsigned short* __restrict__ r_out) {
    int id = blockIdx.x;
    int xcd = id & 7, q = id >> 3;
    int nt = q & 7;                        // 0..7, 128 H-cols
    int mslot = (q >> 3) * 8 + xcd;        // 0..103
    int tt = tiletab[mslot];
    if (tt < 0) return;
    int e = tt >> 8, mt = tt & 255;

    __shared__ unsigned short As[128 * BK];   // 16 KB
    __shared__ unsigned short Bs[128 * BK];   // 16 KB

    int tid = threadIdx.x, lane = tid & 63;
    int wid = tid >> 6, wm = wid >> 1, wn = wid & 1;
    size_t rowbase = (size_t)offs[e] + (size_t)mt * 128;

    const unsigned short* wd = wd_t + (size_t)e * (1024u * 2048u);
    int rsub = tid >> 3;
    int csw = (tid & 7) ^ (rsub & 7);
    const unsigned short* pA[4];
    const unsigned short* pB[4];
#pragma unroll
    for (int i = 0; i < 4; i++) {
        pA[i] = h + (rowbase + i * 32 + rsub) * INTER + csw * 8;
        pB[i] = wd + (size_t)(nt * 128 + i * 32 + rsub) * INTER + csw * 8;
    }
    unsigned short* lA = As + tid * 8;
    unsigned short* lB = Bs + tid * 8;

    f32x4 acc[4][4];
#pragma unroll
    for (int i = 0; i < 4; i++)
#pragma unroll
        for (int j = 0; j < 4; j++) acc[i][j] = (f32x4)(0.0f);

    int mrow = lane & 15, qq = lane >> 4, x7 = lane & 7;
    for (int k0 = 0; k0 < INTER; k0 += BK) {
#pragma unroll
        for (int i = 0; i < 4; i++) {
            async_ld16(pA[i] + k0, lA + i * 2048);
            async_ld16(pB[i] + k0, lB + i * 2048);
        }
        __syncthreads();
#pragma unroll
        for (int ksub = 0; ksub < 2; ksub++) {
            int ch = ((ksub * 4 + qq) ^ x7) * 8;
            short8 af[4], bf_[4];
#pragma unroll
            for (int mi = 0; mi < 4; mi++)
                af[mi] = *(const short8*)(As + (wm * 64 + mi * 16 + mrow) * BK + ch);
#pragma unroll
            for (int ni = 0; ni < 4; ni++)
                bf_[ni] = *(const short8*)(Bs + (wn * 64 + ni * 16 + mrow) * BK + ch);
#pragma unroll
            for (int mi = 0; mi < 4; mi++)
#pragma unroll
                for (int ni = 0; ni < 4; ni++)
                    acc[mi][ni] = __builtin_amdgcn_mfma_f32_16x16x32_bf16(af[mi], bf_[ni], acc[mi][ni], 0, 0, 0);
        }
        __syncthreads();
    }
#pragma unroll
    for (int mi = 0; mi < 4; mi++)
#pragma unroll
        for (int ni = 0; ni < 4; ni++)
#pragma unroll
            for (int r = 0; r < 4; r++) {
                int m = wm * 64 + mi * 16 + (lane >> 4) * 4 + r;
                int n = nt * 128 + wn * 64 + ni * 16 + (lane & 15);
                r_out[(rowbase + m) * HID + n] = f2bf(acc[mi][ni][r]);
            }
}

// ---------------- combine: out[t] = shared + two routed contributions ----------------
__global__ void combine_kernel(const unsigned short* __restrict__ r_out,
                               const int2* __restrict__ inv, const int* __restrict__ offs,
                               float* __restrict__ out) {
    int t = blockIdx.x, tid = threadIdx.x;
    int2 iv = inv[t];
    size_t r1 = (size_t)(offs[iv.x >> 16] + (iv.x & 0xffff)) * HID;
    size_t r2 = (size_t)(offs[iv.y >> 16] + (iv.y & 0xffff)) * HID;
    size_t rs = (size_t)(offs[NE] + t) * HID;
    int i = tid * 4;
    ushort4 a = *(const ushort4*)(r_out + r1 + i);
    ushort4 b = *(const ushort4*)(r_out + r2 + i);
    ushort4 c = *(const ushort4*)(r_out + rs + i);
    float4 o;
    o.x = bf2f(a.x) + bf2f(b.x) + bf2f(c.x);
    o.y = bf2f(a.y) + bf2f(b.y) + bf2f(c.y);
    o.z = bf2f(a.z) + bf2f(b.z) + bf2f(c.z);
    o.w = bf2f(a.w) + bf2f(b.w) + bf2f(c.w);
    *(float4*)(out + (size_t)t * HID + i) = o;
}

extern "C" void kernel_launch(void* const* d_in, const int* in_sizes, int n_in,
                              void* d_out, int out_size, void* d_ws, size_t ws_size,
                              hipStream_t stream) {
    const float* x   = (const float*)d_in[0];
    const float* rw  = (const float*)d_in[1];
    const float* gup = (const float*)d_in[2];
    const float* dwn = (const float*)d_in[3];
    const float* sgw = (const float*)d_in[4];
    const float* suw = (const float*)d_in[5];
    const float* sdw = (const float*)d_in[6];
    float* out = (float*)d_out;
    float* logits = out + (size_t)T_TOK * HID;

    char* ws = (char*)d_ws;
    int*   cnt        = (int*)(ws + 0);
    int*   offs       = (int*)(ws + 64);
    int*   tiletab    = (int*)(ws + 128);
    int2*  inv        = (int2*)(ws + 4096);
    int*   tok_list   = (int*)(ws + 65536);                       // 9*4096*4
    float* score_list = (float*)(ws + 212992);                    // 9*4096*4
    unsigned short* w_gup_t = (unsigned short*)(ws + 524288);     // 9*4096*1024*2 = 75497472
    unsigned short* w_dwn_t = (unsigned short*)(ws + 76021760);   // 9*1024*2048*2 = 37748736
    unsigned short* xg      = (unsigned short*)(ws + 113770496);  // 13312*1024*2  = 27262976
    unsigned short* h       = (unsigned short*)(ws + 141033472);  // 13312*2048*2  = 54525952
    unsigned short* r_out   = (unsigned short*)(ws + 195559424);  // 13312*1024*2  = 27262976

    hipMemsetAsync(cnt, 0, NE * sizeof(int), stream);

    // weight prep: transpose routed weights to bf16 [N][K]; shared already [N][K]
    {
        dim3 g(4096 / 64, 1024 / 128, NE);
        transpose_cast<<<g, 256, 0, stream>>>(gup, w_gup_t, 1024, 4096,
                                              (size_t)1024 * 4096, (size_t)4096 * 1024);
    }
    {
        dim3 g(1024 / 64, 2048 / 128, NE);
        transpose_cast<<<g, 256, 0, stream>>>(dwn, w_dwn_t, 2048, 1024,
                                              (size_t)2048 * 1024, (size_t)1024 * 2048);
    }
    unsigned short* wg8 = w_gup_t + (size_t)NE * 4096 * 1024;
    unsigned short* wd8 = w_dwn_t + (size_t)NE * 1024 * 2048;
    {
        dim3 g(2048, 3);
        prep_cast<<<g, 256, 0, stream>>>(sgw, suw, sdw, wg8, wg8 + 2048 * 1024, wd8);
    }

    router_kernel<<<T_TOK / 4, 256, 0, stream>>>(x, rw, logits, cnt, tok_list, score_list, inv);
    finalize_kernel<<<1, 256, 0, stream>>>(cnt, offs, tiletab, tok_list, score_list);
    gather_kernel<<<MAXT, 256, 0, stream>>>(x, tiletab, offs, tok_list, xg);

    moe_g1<<<MAXT * (INTER / 64), 256, 0, stream>>>(xg, w_gup_t, tiletab, offs, score_list, h);
    moe_g2<<<MAXT * (HID / 128), 256, 0, stream>>>(h, w_dwn_t, tiletab, offs, r_out);
    combine_kernel<<<T_TOK, 256, 0, stream>>>(r_out, inv, offs, out);
}